// Round 10
// baseline (272.682 us; speedup 1.0000x reference)
//
#include <hip/hip_runtime.h>
#include <math.h>
#include <stdint.h>

typedef unsigned short u16;
typedef __attribute__((ext_vector_type(8))) short short8;
typedef __attribute__((ext_vector_type(4))) float f32x4;

// gate scale: 0.125 (attn scale) * log2(e)  -> p = exp2(s * gate)
#define GATE_SCALE 0.18033688011112042f
#define LOG2E 1.4426950408889634f

#if __has_builtin(__builtin_amdgcn_exp2f)
#define FEXP2(x) __builtin_amdgcn_exp2f(x)
#else
#define FEXP2(x) exp2f(x)
#endif

// GATE_SCALE * sigmoid(m), f32, fast rcp (~1 ulp; previous path rounded the
// gate to bf16, so this is strictly more accurate).
__device__ __forceinline__ float fsig(float m) {
    float e = FEXP2(m * -LOG2E);
#if __has_builtin(__builtin_amdgcn_rcpf)
    return GATE_SCALE * __builtin_amdgcn_rcpf(1.f + e);
#else
    return GATE_SCALE / (1.f + e);
#endif
}

// fp32 -> bf16 round-to-nearest-even
__device__ __forceinline__ u16 f2b(float f) {
    union { float f; unsigned u; } v; v.f = f;
    unsigned r = v.u + 0x7fffu + ((v.u >> 16) & 1u);
    return (u16)(r >> 16);
}
// fp32 -> bf16 round-half-up
__device__ __forceinline__ u16 f2b_hu(float f) {
    union { float f; unsigned u; } v; v.f = f;
    return (u16)((v.u + 0x8000u) >> 16);
}

// async global->LDS, 16B per lane. lds base wave-uniform; HW adds lane*16.
#define GLL16(gsrc, ldsbase) __builtin_amdgcn_global_load_lds(                    \
    (__attribute__((address_space(1))) void*)(uintptr_t)(gsrc),                   \
    (__attribute__((address_space(3))) void*)(uint32_t)(uintptr_t)(ldsbase),      \
    16, 0, 0)

// ---------------------------------------------------------------------------
// K0: convert x / w_qkv / w_proj to bf16 (gate pipeline deleted in R10 --
// flash computes sigmoid(mask) inline).
// ---------------------------------------------------------------------------
#define NX4  1572864   // 6291456/4
#define NW14 442368
#define NW24 147456
#define NXW4 (NX4 + NW14 + NW24)   // 2162688 -> 8448 blocks

__global__ __launch_bounds__(256) void prep_xw(
    const float4* __restrict__ x, const float4* __restrict__ wq,
    const float4* __restrict__ wp,
    ushort4* __restrict__ xb, ushort4* __restrict__ wqb,
    ushort4* __restrict__ wpb)
{
    size_t i = (size_t)blockIdx.x * 256 + threadIdx.x;
    float4 v; ushort4* dst; size_t j;
    if (i < NX4)            { j = i;               v = x[j];  dst = xb;  }
    else if (i < NX4 + NW14){ j = i - NX4;         v = wq[j]; dst = wqb; }
    else                    { j = i - (NX4 + NW14);v = wp[j]; dst = wpb; }
    ushort4 o; o.x = f2b(v.x); o.y = f2b(v.y); o.z = f2b(v.z); o.w = f2b(v.w);
    dst[j] = o;
}

// ---------------------------------------------------------------------------
// K1: QKV GEMM -- R8-measured form (52.2 us): 128x128 tile, 4 waves,
// acc[4][4], depth-2 double-buffer, 2-phase loop (vmcnt(0); barrier;
// stage(next); ds_read; MFMA), 32 KB LDS -> 5 blocks/CU, grid 1152 in one
// dispatch round, conflict-free swizzles, XCD chunking (144/XCD).
// q/k written (B,H,N,64); V written TRANSPOSED (B,H,64,N).
// ---------------------------------------------------------------------------
__global__ __launch_bounds__(256) void qkv_gemm(
    const u16* __restrict__ xb, const u16* __restrict__ wb,
    u16* __restrict__ qb, u16* __restrict__ kb, u16* __restrict__ vb)
{
    __shared__ u16 As[2][4096];
    __shared__ u16 Bs[2][4096];
    const int t = threadIdx.x, l = t & 63, w = t >> 6;
    const int wm = (w & 1) * 64, wn = (w >> 1) * 64;

    const int orig = blockIdx.x + 18 * blockIdx.y;   // gridDim = (18, 64)
    const int nid = (orig & 7) * 144 + (orig >> 3);  // 1152 blocks, 144/XCD
    const int m0 = (nid / 18) * 128, c0 = (nid % 18) * 128;

    f32x4 acc[4][4];
    #pragma unroll
    for (int i = 0; i < 4; ++i)
        #pragma unroll
        for (int j = 0; j < 4; ++j) { f32x4 z = {0.f,0.f,0.f,0.f}; acc[i][j] = z; }

    const int srow = l >> 2, sseg = l & 3;
    const int gcol = ((sseg ^ ((srow >> 1) & 3)) << 3);
    const u16* a0 = xb + (size_t)(m0 + w * 16 + srow) * 768 + gcol;
    const u16* a1 = a0 + (size_t)64 * 768;
    const u16* b0p = wb + (size_t)(c0 + w * 16 + srow) * 768 + gcol;
    const u16* b1p = b0p + (size_t)64 * 768;
    const int wofs = w * 512;

    const int fr = l & 15, fq = l >> 4;
    const int fseg = (fq ^ ((fr >> 1) & 3)) << 3;

    auto stage = [&](int bi, int koff) {
        GLL16(a0 + koff, &As[bi][wofs]);
        GLL16(a1 + koff, &As[bi][2048 + wofs]);
        GLL16(b0p + koff, &Bs[bi][wofs]);
        GLL16(b1p + koff, &Bs[bi][2048 + wofs]);
    };

    stage(0, 0);

    for (int kt = 0; kt < 24; ++kt) {
        asm volatile("s_waitcnt vmcnt(0)" ::: "memory");
        __builtin_amdgcn_s_barrier();
        if (kt < 23) stage((kt + 1) & 1, (kt + 1) * 32);
        const u16* A = As[kt & 1];
        const u16* B = Bs[kt & 1];
        short8 af[4], bf[4];
        #pragma unroll
        for (int mt = 0; mt < 4; ++mt)
            af[mt] = *(const short8*)&A[(wm + mt * 16 + fr) * 32 + fseg];
        #pragma unroll
        for (int nt = 0; nt < 4; ++nt)
            bf[nt] = *(const short8*)&B[(wn + nt * 16 + fr) * 32 + fseg];
        #pragma unroll
        for (int mt = 0; mt < 4; ++mt)
            #pragma unroll
            for (int nt = 0; nt < 4; ++nt)
                acc[mt][nt] = __builtin_amdgcn_mfma_f32_16x16x32_bf16(
                    af[mt], bf[nt], acc[mt][nt], 0, 0, 0);
    }

    const int b = m0 >> 10;
    const int n0 = m0 & 1023;
    #pragma unroll
    for (int nt = 0; nt < 4; ++nt) {
        const int c = c0 + wn + nt * 16 + fr;
        const int which = c / 768;
        const int rem = c - which * 768;
        const int h = rem >> 6, d = rem & 63;
        if (which < 2) {
            u16* dst = ((which == 0) ? qb : kb)
                       + ((size_t)(b * 12 + h) * 1024) * 64 + d;
            #pragma unroll
            for (int mt = 0; mt < 4; ++mt)
                #pragma unroll
                for (int r = 0; r < 4; ++r) {
                    const int n = n0 + wm + mt * 16 + fq * 4 + r;
                    dst[(size_t)n * 64] = f2b(acc[mt][nt][r]);
                }
        } else {
            u16* dst = vb + ((size_t)(b * 12 + h) * 64 + d) * 1024
                          + n0 + wm + fq * 4;
            #pragma unroll
            for (int mt = 0; mt < 4; ++mt) {
                ushort4 pk;
                pk.x = f2b(acc[mt][nt][0]); pk.y = f2b(acc[mt][nt][1]);
                pk.z = f2b(acc[mt][nt][2]); pk.w = f2b(acc[mt][nt][3]);
                *(ushort4*)(dst + mt * 16) = pk;
            }
        }
    }
}

// ---------------------------------------------------------------------------
// K2: flash attention. R10 = R6 structure with the gate computed INLINE
// from mask (f32), deleting the entire gate-prep pipeline (48 MB mask read
// + 25 MB gperm write in qkv_gate + gperm re-reads here):
//  * per fragment value (qh,i,nt) the lane loads
//    mask[h][q0+qh*64+16w+4fq+i][kt*64+nt*16+fr] -- per load inst, 16-lane
//    groups read 64 contiguous bytes; working set L3-resident.
//  * 32 scalar loads prefetched ONE kt ahead (same slot as old gperm
//    prefetch); counted wait becomes vmcnt(32) (32 gate loads may stay
//    outstanding while draining own 4 staging GLL16s).
//  * gate = GATE_SCALE*sigmoid(m) via exp2+rcp (f32 -- more accurate than
//    the old bf16-rounded gate).
// VGPR ~116 (was 84; +64 gate f32 regs - 32 old): under the 170 cap at
// 3 blocks/CU (R3 spill lesson re-checked). Everything else R6-verified:
// K/V dbuf + one raw barrier, K/V-colocating XCD remap, setprio.
// ---------------------------------------------------------------------------
__global__ __launch_bounds__(256, 3) void flash_attn(
    const u16* __restrict__ qb, const u16* __restrict__ kb,
    const u16* __restrict__ vt, const float* __restrict__ mask,
    u16* __restrict__ aob)
{
    __shared__ u16 Ks[2][4096], Vts[2][4096], Ps[4096];
    const int t = threadIdx.x, l = t & 63, w = t >> 6;
    const int bid = blockIdx.x;
    // K/V-colocating remap: all 8 qtb-siblings of one (b,h) on one XCD
    const int xcd = bid & 7, jj = bid >> 3;
    const int bh = (jj % 12) * 8 + xcd;
    const int qtb = jj / 12;
    const int h = bh % 12, b = bh / 12;
    const int q0 = qtb * 128;

    const u16* hq = qb + (size_t)bh * 65536;
    const u16* hk = kb + (size_t)bh * 65536;
    const u16* hv = vt + (size_t)bh * 65536;

    const int sr = l >> 3, ss = l & 7;
    const int sg = ((ss ^ (sr & 7)) << 3);
    const int j0 = w * 2, j1 = j0 + 1;

    const int fq = l >> 4, fr = l & 15;
    const int sega = ((fq ^ (fr & 7)) << 3);
    const int segb = (((4 + fq) ^ (fr & 7)) << 3);

    // per-lane mask base: row block q0+16w, col fr
    const float* hm = mask + ((size_t)h * 1024 + q0 + 16 * w) * 1024 + fr;
    // value (qh,i,nt) at kt: hm[(qh*64 + 4*fq + i)*1024 + kt*64 + nt*16]
    auto gload = [&](float* dst, int ktv) {
        #pragma unroll
        for (int qh = 0; qh < 2; ++qh)
            #pragma unroll
            for (int i = 0; i < 4; ++i)
                #pragma unroll
                for (int nt = 0; nt < 4; ++nt)
                    dst[qh * 16 + i * 4 + nt] =
                        hm[(size_t)(qh * 64 + 4 * fq + i) * 1024 + ktv * 64 + nt * 16];
    };

    // Q A-frags (kt-invariant) direct from global
    short8 aq[2][2];
    #pragma unroll
    for (int qh = 0; qh < 2; ++qh) {
        const u16* qrow = hq + (size_t)(q0 + qh * 64 + 16 * w + fr) * 64;
        aq[qh][0] = *(const short8*)(qrow + fq * 8);
        aq[qh][1] = *(const short8*)(qrow + 32 + fq * 8);
    }

    // stage kt=0 K/V into buf 0
    GLL16(hk + (size_t)(j0 * 8 + sr) * 64 + sg, &Ks[0][j0 * 512]);
    GLL16(hk + (size_t)(j1 * 8 + sr) * 64 + sg, &Ks[0][j1 * 512]);
    GLL16(hv + (size_t)(j0 * 8 + sr) * 1024 + sg, &Vts[0][j0 * 512]);
    GLL16(hv + (size_t)(j1 * 8 + sr) * 1024 + sg, &Vts[0][j1 * 512]);
    __builtin_amdgcn_sched_barrier(0);

    // gate prefetch for kt=0 (raw mask values, f32)
    float gn[32];
    gload(gn, 0);

    float l_part[2][4] = {{0.f,0.f,0.f,0.f},{0.f,0.f,0.f,0.f}};
    f32x4 o[2][4];
    #pragma unroll
    for (int qh = 0; qh < 2; ++qh)
        #pragma unroll
        for (int nt = 0; nt < 4; ++nt) { f32x4 z = {0.f,0.f,0.f,0.f}; o[qh][nt] = z; }

    for (int kt = 0; kt < 16; ++kt) {
        // drain own 4 staging GLL16s; the 32 gate loads may stay outstanding
        asm volatile("s_waitcnt vmcnt(32)" ::: "memory");
        __builtin_amdgcn_s_barrier();

        if (kt < 15) {                          // stage kt+1 into buf^1
            const size_t ko = (size_t)(kt + 1) * 64;
            u16* kd = &Ks[(kt + 1) & 1][0];
            u16* vd = &Vts[(kt + 1) & 1][0];
            GLL16(hk + (ko + j0 * 8 + sr) * 64 + sg, kd + j0 * 512);
            GLL16(hk + (ko + j1 * 8 + sr) * 64 + sg, kd + j1 * 512);
            GLL16(hv + (size_t)(j0 * 8 + sr) * 1024 + ko + sg, vd + j0 * 512);
            GLL16(hv + (size_t)(j1 * 8 + sr) * 1024 + ko + sg, vd + j1 * 512);
            __builtin_amdgcn_sched_barrier(0);  // keep GLL16s older than gate loads
        }

        float g[32];
        #pragma unroll
        for (int s = 0; s < 32; ++s) g[s] = gn[s];
        if (kt < 15) gload(gn, kt + 1);         // gate prefetch, 1 ahead

        const u16* KS = &Ks[kt & 1][0];
        const u16* VS = &Vts[kt & 1][0];

        // S = Q . K^T for both halves; k-frags read once, used twice
        f32x4 sv[2][4];
        __builtin_amdgcn_s_setprio(1);
        #pragma unroll
        for (int nt = 0; nt < 4; ++nt) {
            short8 kf0 = *(const short8*)&KS[(nt * 16 + fr) * 64 + sega];
            short8 kf1 = *(const short8*)&KS[(nt * 16 + fr) * 64 + segb];
            f32x4 z0 = {0.f,0.f,0.f,0.f};
            z0 = __builtin_amdgcn_mfma_f32_16x16x32_bf16(aq[0][0], kf0, z0, 0, 0, 0);
            z0 = __builtin_amdgcn_mfma_f32_16x16x32_bf16(aq[0][1], kf1, z0, 0, 0, 0);
            sv[0][nt] = z0;
            f32x4 z1 = {0.f,0.f,0.f,0.f};
            z1 = __builtin_amdgcn_mfma_f32_16x16x32_bf16(aq[1][0], kf0, z1, 0, 0, 0);
            z1 = __builtin_amdgcn_mfma_f32_16x16x32_bf16(aq[1][1], kf1, z1, 0, 0, 0);
            sv[1][nt] = z1;
        }
        __builtin_amdgcn_s_setprio(0);

        // inline gate (sigmoid) + exp + P->LDS per half (Ps per-wave
        // private); ap frags captured before Ps reuse next iter.
        short8 ap[2][2];
        #pragma unroll
        for (int qh = 0; qh < 2; ++qh) {
            #pragma unroll
            for (int i = 0; i < 4; ++i) {
                const int pr = 4 * fq + i;
                #pragma unroll
                for (int nt = 0; nt < 4; ++nt) {
                    const float gv = fsig(g[qh * 16 + i * 4 + nt]);
                    const float p = FEXP2(sv[qh][nt][i] * gv);
                    l_part[qh][i] += p;
                    const int col = nt * 16 + fr;
                    Ps[w * 1024 + pr * 64 + (((col >> 3) ^ (pr & 7)) << 3) + (col & 7)]
                        = f2b_hu(p);
                }
            }
            ap[qh][0] = *(const short8*)&Ps[w * 1024 + fr * 64 + sega];
            ap[qh][1] = *(const short8*)&Ps[w * 1024 + fr * 64 + segb];
        }

        // O += P . V for both halves; v-frags read once, used twice
        __builtin_amdgcn_s_setprio(1);
        #pragma unroll
        for (int nt = 0; nt < 4; ++nt) {
            short8 vf0 = *(const short8*)&VS[(nt * 16 + fr) * 64 + sega];
            short8 vf1 = *(const short8*)&VS[(nt * 16 + fr) * 64 + segb];
            o[0][nt] = __builtin_amdgcn_mfma_f32_16x16x32_bf16(ap[0][0], vf0, o[0][nt], 0, 0, 0);
            o[0][nt] = __builtin_amdgcn_mfma_f32_16x16x32_bf16(ap[0][1], vf1, o[0][nt], 0, 0, 0);
            o[1][nt] = __builtin_amdgcn_mfma_f32_16x16x32_bf16(ap[1][0], vf0, o[1][nt], 0, 0, 0);
            o[1][nt] = __builtin_amdgcn_mfma_f32_16x16x32_bf16(ap[1][1], vf1, o[1][nt], 0, 0, 0);
        }
        __builtin_amdgcn_s_setprio(0);
    }

    // deferred l reduction + epilogue per half
    #pragma unroll
    for (int qh = 0; qh < 2; ++qh) {
        #pragma unroll
        for (int i = 0; i < 4; ++i) {
            float s = l_part[qh][i];
            s += __shfl_xor(s, 1, 16);
            s += __shfl_xor(s, 2, 16);
            s += __shfl_xor(s, 4, 16);
            s += __shfl_xor(s, 8, 16);
            const float inv = 1.f / s;
            const int n = q0 + qh * 64 + 16 * w + 4 * fq + i;
            const size_t rowoff = ((size_t)b * 1024 + n) * 768 + h * 64;
            #pragma unroll
            for (int nt = 0; nt < 4; ++nt)
                aob[rowoff + nt * 16 + fr] = f2b(o[qh][nt][i] * inv);
        }
    }
}

// ---------------------------------------------------------------------------
// K3: output projection. R9-verified: 128x256 block tile, per-wave 128x64
// (acc[8][4]), depth-3 vmcnt(6) pipeline, grid 192 (24/XCD). fp32 out+bias.
// ---------------------------------------------------------------------------
__global__ __launch_bounds__(256, 2) void proj_gemm(
    const u16* __restrict__ aob, const u16* __restrict__ wb,
    const float* __restrict__ bproj, float* __restrict__ out)
{
    __shared__ u16 As[3][4096];
    __shared__ u16 Bs[3][8192];
    const int t = threadIdx.x, l = t & 63, w = t >> 6;
    const int wc = w * 64;

    const int orig = blockIdx.x;                 // 192 blocks
    const int nid = (orig & 7) * 24 + (orig >> 3);
    const int m0 = (nid / 3) * 128, c0 = (nid % 3) * 256;

    f32x4 acc[8][4];
    #pragma unroll
    for (int i = 0; i < 8; ++i)
        #pragma unroll
        for (int j = 0; j < 4; ++j) { f32x4 z = {0.f,0.f,0.f,0.f}; acc[i][j] = z; }

    const int srow = l >> 2, sseg = l & 3;
    const int gcol = ((sseg ^ ((srow >> 1) & 3)) << 3);
    const u16* aA = aob + (size_t)(m0 + w * 16 + srow) * 768 + gcol;
    const u16* aB = wb + (size_t)(c0 + w * 16 + srow) * 768 + gcol;

    const int fr = l & 15, fq = l >> 4;
    const int fseg = (fq ^ ((fr >> 1) & 3)) << 3;

    auto stage = [&](int bi, int koff) {
        GLL16(aA + koff,                      &As[bi][(w + 0) * 512]);
        GLL16(aA + koff + (size_t)64 * 768,   &As[bi][(w + 4) * 512]);
        GLL16(aB + koff,                      &Bs[bi][(w + 0) * 512]);
        GLL16(aB + koff + (size_t)64 * 768,   &Bs[bi][(w + 4) * 512]);
        GLL16(aB + koff + (size_t)128 * 768,  &Bs[bi][(w + 8) * 512]);
        GLL16(aB + koff + (size_t)192 * 768,  &Bs[bi][(w + 12) * 512]);
    };

    stage(0, 0);
    stage(1, 32);

    int cur = 0;
    for (int kt = 0; kt < 24; ++kt) {
        if (kt < 23) asm volatile("s_waitcnt vmcnt(6)" ::: "memory");
        else         asm volatile("s_waitcnt vmcnt(0)" ::: "memory");
        __builtin_amdgcn_s_barrier();
        if (kt < 22) {
            const int nn = (cur == 0) ? 2 : cur - 1;
            stage(nn, (kt + 2) * 32);
        }
        const u16* A = As[cur];
        const u16* B = Bs[cur];
        short8 af[8], bf[4];
        #pragma unroll
        for (int mt = 0; mt < 8; ++mt)
            af[mt] = *(const short8*)&A[(mt * 16 + fr) * 32 + fseg];
        #pragma unroll
        for (int nt = 0; nt < 4; ++nt)
            bf[nt] = *(const short8*)&B[(wc + nt * 16 + fr) * 32 + fseg];
        #pragma unroll
        for (int mt = 0; mt < 8; ++mt)
            #pragma unroll
            for (int nt = 0; nt < 4; ++nt)
                acc[mt][nt] = __builtin_amdgcn_mfma_f32_16x16x32_bf16(
                    af[mt], bf[nt], acc[mt][nt], 0, 0, 0);
        cur = (cur == 2) ? 0 : cur + 1;
    }

    #pragma unroll
    for (int nt = 0; nt < 4; ++nt) {
        const int c = c0 + wc + nt * 16 + fr;
        const float bias = bproj[c];
        #pragma unroll
        for (int mt = 0; mt < 8; ++mt)
            #pragma unroll
            for (int r = 0; r < 4; ++r) {
                const int m = m0 + mt * 16 + fq * 4 + r;
                out[(size_t)m * 768 + c] = acc[mt][nt][r] + bias;
            }
    }
}

// ---------------------------------------------------------------------------
extern "C" void kernel_launch(void* const* d_in, const int* in_sizes, int n_in,
                              void* d_out, int out_size, void* d_ws, size_t ws_size,
                              hipStream_t stream)
{
    const float* x     = (const float*)d_in[0];
    const float* wqkv  = (const float*)d_in[1];
    const float* wproj = (const float*)d_in[2];
    const float* bproj = (const float*)d_in[3];
    const float* mask  = (const float*)d_in[4];
    float* out = (float*)d_out;

    char* ws = (char*)d_ws;
    // gperm region retired (gate computed inline in flash); offsets kept.
    u16* xb     = (u16*)(ws + 25165824);    // 12,582,912 B
    u16* wqkvb  = (u16*)(ws + 37748736);    //  3,538,944 B
    u16* wprojb = (u16*)(ws + 41287680);    //  1,179,648 B
    u16* qb     = (u16*)(ws + 42467328);    // 12,582,912 B
    u16* kb     = (u16*)(ws + 55050240);    // 12,582,912 B
    u16* vb     = (u16*)(ws + 67633152);    // 12,582,912 B (transposed: B,H,64,N)
    u16* aob    = (u16*)(ws + 80216064);    // 12,582,912 B

    prep_xw<<<NXW4 / 256, 256, 0, stream>>>(
        (const float4*)x, (const float4*)wqkv, (const float4*)wproj,
        (ushort4*)xb, (ushort4*)wqkvb, (ushort4*)wprojb);

    qkv_gemm<<<dim3(18, 64), 256, 0, stream>>>(xb, wqkvb, qb, kb, vb);

    flash_attn<<<768, 256, 0, stream>>>(qb, kb, vb, mask, aob);

    proj_gemm<<<192, 256, 0, stream>>>(aob, wprojb, bproj, out);
}